// Round 11
// baseline (168.407 us; speedup 1.0000x reference)
//
#include <hip/hip_runtime.h>

// NearestNeighbor b=8, d=256, n=m=4096.
// Round 11: occupancy restructure — 512-thread blocks, 8 waves x (64 rows x 16 cols),
// <=128 VGPR/wave -> 4 waves/SIMD. Frag-tiled fp8 panels, af in regs (shared rows),
// LDS = B dbuf 32KB, lockstep r8 schedule. prep/finalize layouts verified r8-r10.

typedef unsigned int uint;
typedef unsigned char uchar;
typedef int i32x4 __attribute__((ext_vector_type(4)));
typedef int i32x8 __attribute__((ext_vector_type(8)));
typedef float f32x4 __attribute__((ext_vector_type(4)));

constexpr int B_ = 8, D_ = 256, N_ = 4096;
constexpr int CSPLIT = 2;                      // column split
constexpr int MT_ITERS = (N_ / CSPLIT) / 128;  // 16 tiles of 128 cols

// Unified frag-tiled panel layout (per batch, 1 MB):
// element (n,k): seg=n>>7, q=(n>>6)&1, r4=(n>>4)&3, i16=n&15;
//               ks=k>>7, g=(k>>5)&3, h=(k>>4)&1, kb=k&15
// off = seg*32768 + ks*16384 + ((q*4+r4)*2+h)*1024 + (g*16+i16)*16 + kb

// workspace layout (bytes)
constexpr size_t SZ_PANEL = (size_t)B_ * N_ * D_;        // 8.39 MB (fp8)
constexpr size_t OFF_AT = 0;
constexpr size_t OFF_BT = SZ_PANEL;
constexpr size_t OFF_PR = 2 * SZ_PANEL;                  // row partials: 16 slots
constexpr size_t SZ_PR  = (size_t)16 * B_ * N_ * 8;      // 4.2 MB
constexpr size_t OFF_PC = OFF_PR + SZ_PR;                // col partials: 64 slots

// f32 -> OCP e4m3fn (RNE, saturating).
__device__ __forceinline__ uchar f2e4m3(float f) {
  uint u = __float_as_uint(f);
  uint s = (u >> 24) & 0x80u;
  uint mag = u & 0x7FFFFFFFu;
  if (mag >= 0x43E00000u) return (uchar)(s | 0x7Eu);
  int e = (int)(mag >> 23) - 127;
  if (e >= -6) {
    uint m = (mag >> 20) & 7u;
    uint rem = mag & 0xFFFFFu;
    m += (rem > 0x80000u) || (rem == 0x80000u && (m & 1u));
    uint ef = (uint)(e + 7);
    if (m == 8u) { m = 0u; ef += 1u; }
    if (ef >= 16u) return (uchar)(s | 0x7Eu);
    return (uchar)(s | (ef << 3) | m);
  } else {
    int q = __float2int_rn(__uint_as_float(mag) * 512.0f);
    if (q >= 8) return (uchar)(s | 0x08u);
    return (uchar)(s | (uint)q);
  }
}

__device__ __forceinline__ void glds16(const void* g, void* l) {
  __builtin_amdgcn_global_load_lds(
      (const __attribute__((address_space(1))) void*)(uintptr_t)(g),
      (__attribute__((address_space(3))) void*)(uint32_t)(uintptr_t)(l),
      16, 0, 0);
}

__device__ __forceinline__ float packkey(float v, uint mask, uint tag) {
  return __uint_as_float((__float_as_uint(v) & mask) | tag);
}

__device__ __forceinline__ float med3f(float a, float b, float c) {
#if __has_builtin(__builtin_amdgcn_fmed3f)
  return __builtin_amdgcn_fmed3f(a, b, c);
#else
  return fmaxf(fminf(a, b), fminf(fmaxf(a, b), c));
#endif
}

__device__ __forceinline__ void top2(float& s1, float& s2, float k) {
  const float m = med3f(s1, s2, k);
  s1 = fmaxf(s1, k);
  s2 = m;
}

__device__ __forceinline__ void top2p(float& s1, float& s2, float k0, float k1) {
  const float mid = med3f(s1, k0, k1);
  s1 = fmaxf(fmaxf(s1, k0), k1);
  s2 = fmaxf(s2, mid);
}

__device__ __forceinline__ void top2merge(float& s1, float& s2, float o1, float o2) {
  const float lo = fminf(s1, o1);
  s1 = fmaxf(s1, o1);
  s2 = fmaxf(lo, fmaxf(s2, o2));
}

// ---- prep: [b][256][4096] f32 -> frag-tiled fp8 panel (verified r8-r10) ----
__global__ __launch_bounds__(256)
void prep_kernel(const float* __restrict__ in0, const float* __restrict__ in1,
                 uchar* __restrict__ At, uchar* __restrict__ Bt)
{
  __shared__ uchar tile[128][44];
  const int bz = blockIdx.z;
  const float* src = (bz < 8) ? in0 : in1;
  uchar* dst = (bz < 8) ? At : Bt;
  const int b = bz & 7;
  const int n0 = blockIdx.x * 128;
  const int k0b = blockIdx.y * 32;
  const int t = threadIdx.x;

  const int kq = t >> 5;
  const int n4 = (t & 31) * 4;
  const float* pin = src + ((size_t)b * D_ + k0b + kq * 4) * N_ + n0 + n4;
  float4 v[4];
  #pragma unroll
  for (int j = 0; j < 4; ++j) v[j] = *(const float4*)(pin + (size_t)j * N_);
  #pragma unroll
  for (int i = 0; i < 4; ++i) {
    uchar4 o = make_uchar4(f2e4m3(((const float*)&v[0])[i]),
                           f2e4m3(((const float*)&v[1])[i]),
                           f2e4m3(((const float*)&v[2])[i]),
                           f2e4m3(((const float*)&v[3])[i]));
    *(uchar4*)&tile[n4 + i][kq * 4] = o;
  }
  __syncthreads();

  const int nl = t & 127, h = t >> 7;
  const int kg = k0b + h * 16;
  const int ks = kg >> 7, g = (kg >> 5) & 3, hh = (kg >> 4) & 1;
  const int q = (nl >> 6) & 1, r4 = (nl >> 4) & 3, i16 = nl & 15;
  i32x4 val;
  #pragma unroll
  for (int j = 0; j < 4; ++j)
    val[j] = *(const int*)&tile[nl][h * 16 + j * 4];
  uchar* po = dst + (size_t)b * (N_ * D_) + (size_t)blockIdx.x * 32768 +
              ks * 16384 + ((q * 4 + r4) * 2 + hh) * 1024 + (g * 16 + i16) * 16;
  *(i32x4*)po = val;
}

// ---- fused GEMM (MX-fp8 K=128) + dual-direction top-2, high-occupancy ----
// Block: 512 thr = 8 waves; 64 rows x 2048-col scan; wave wn = 64 rows x 16 cols.
// Row keys: 21 bits | 11-bit inv scan-col tag. Col keys: 26 bits | 6-bit inv row tag.
__global__ __launch_bounds__(512, 4)
void nn_pass(const uchar* __restrict__ A, const uchar* __restrict__ Bp,
             uint2* __restrict__ partR, uint2* __restrict__ partC)
{
  __shared__ uchar Bs[2][16384];   // B half-tile double buffer (32 KB)

  const int t = threadIdx.x;
  const int bid = blockIdx.x;
  const int b = bid & 7;                   // XCD-pinned batch
  const int rb = (bid >> 3) & 63;          // 64-row block
  const int cs = bid >> 9;                 // 0..1
  const size_t bOff = (size_t)b * (N_ * D_);
  const int r0 = rb * 64;

  const int l = t & 63, wn = t >> 6;       // 8 waves: 16-col slice each
  const int l15 = l & 15, g = l >> 4;
  const int lds0 = t * 16;                 // 512*16 = 8192

  const uchar* Apan = A + bOff + (size_t)(rb >> 1) * 32768;   // seg
  const int q = rb & 1;                                        // 64-row half of seg
  const uchar* Bb = Bp + bOff + (size_t)cs * 524288;           // cs half: 16 tiles x 32KB

  auto STAGE = [&](int tile, int ksl, int slot) {
    const uchar* src = Bb + (size_t)tile * 32768 + (size_t)ksl * 16384;
    #pragma unroll
    for (int i = 0; i < 2; ++i)
      glds16(src + i * 8192 + lds0, (char*)Bs[slot] + i * 8192 + lds0);
  };

  // ---- prologue: stage (0,ks0) -> buf0; A-frags (block's 64 rows, held in regs) ----
  STAGE(0, 0, 0);
  i32x8 af[2][4];
  #pragma unroll
  for (int ks = 0; ks < 2; ++ks)
    #pragma unroll
    for (int mi = 0; mi < 4; ++mi) {
      const uchar* p = Apan + ks * 16384 + ((q * 4 + mi) * 2) * 1024 + l * 16;
      const i32x4 lo = *(const i32x4*)p;
      const i32x4 hi = *(const i32x4*)(p + 1024);
      af[ks][mi] = __builtin_shufflevector(lo, hi, 0, 1, 2, 3, 4, 5, 6, 7);
    }
  __syncthreads();

  const float NEG = __uint_as_float(0xFF800000u);  // -inf
  float rs1[4][4], rs2[4][4];
  #pragma unroll
  for (int mi = 0; mi < 4; ++mi)
    #pragma unroll
    for (int rg = 0; rg < 4; ++rg) { rs1[mi][rg] = NEG; rs2[mi][rg] = NEG; }

  float cp1 = NEG, cp2 = NEG;   // deferred partC value (1 col/lane)

  #pragma unroll 1
  for (int mt = 0; mt < MT_ITERS; ++mt) {
    // deferred partC store for tile mt-1 (drains at the next barrier, covered)
    if (mt > 0 && g == 0)
      partC[((size_t)rb * B_ + b) * N_ + cs * 2048 + (mt - 1) * 128 + wn * 16 + l15] =
          make_uint2(__float_as_uint(cp1), __float_as_uint(cp2));

    f32x4 acc[4];
    #pragma unroll
    for (int mi = 0; mi < 4; ++mi) acc[mi] = (f32x4){0.f, 0.f, 0.f, 0.f};

    // ---- half ks=0: stage (mt,ks1)->buf1; compute from buf0 ----
    STAGE(mt, 1, 1);
    {
      const char* cB = (const char*)Bs[0] + wn * 2048 + l * 16;
      const i32x4 lo = *(const i32x4*)cB;
      const i32x4 hi = *(const i32x4*)(cB + 1024);
      const i32x8 bf = __builtin_shufflevector(lo, hi, 0, 1, 2, 3, 4, 5, 6, 7);
      __builtin_amdgcn_s_setprio(1);
      #pragma unroll
      for (int mi = 0; mi < 4; ++mi)
        acc[mi] = __builtin_amdgcn_mfma_scale_f32_16x16x128_f8f6f4(
            af[0][mi], bf, acc[mi], 0, 0, 0, 127, 0, 127);
      __builtin_amdgcn_s_setprio(0);
    }
    __syncthreads();

    // ---- half ks=1: stage (mt+1,ks0)->buf0; compute from buf1; fold ----
    if (mt + 1 < MT_ITERS) STAGE(mt + 1, 0, 0);
    {
      const char* cB = (const char*)Bs[1] + wn * 2048 + l * 16;
      const i32x4 lo = *(const i32x4*)cB;
      const i32x4 hi = *(const i32x4*)(cB + 1024);
      const i32x8 bf = __builtin_shufflevector(lo, hi, 0, 1, 2, 3, 4, 5, 6, 7);
      __builtin_amdgcn_s_setprio(1);
      #pragma unroll
      for (int mi = 0; mi < 4; ++mi)
        acc[mi] = __builtin_amdgcn_mfma_scale_f32_16x16x128_f8f6f4(
            af[1][mi], bf, acc[mi], 0, 0, 0, 127, 0, 127);
      __builtin_amdgcn_s_setprio(0);
    }

    // ---- fold: row direction (lane's single column; per-row rs slots) ----
    const uint tagc = (uint)(2047 - (mt * 128 + wn * 16 + l15));
    #pragma unroll
    for (int mi = 0; mi < 4; ++mi)
      #pragma unroll
      for (int rg = 0; rg < 4; ++rg)
        top2(rs1[mi][rg], rs2[mi][rg], packkey(acc[mi][rg], 0xFFFFF800u, tagc));

    // ---- fold: col direction (16 rows in-lane, then merge across g) ----
    {
      const uint tgb = (uint)(63 - g * 4);
      float c1 = NEG, c2 = NEG;
      #pragma unroll
      for (int mi = 0; mi < 4; ++mi) {
        const float k0 = packkey(acc[mi][0], 0xFFFFFFC0u, tgb - (uint)(mi * 16));
        const float k1 = packkey(acc[mi][1], 0xFFFFFFC0u, tgb - (uint)(mi * 16 + 1));
        const float k2 = packkey(acc[mi][2], 0xFFFFFFC0u, tgb - (uint)(mi * 16 + 2));
        const float k3 = packkey(acc[mi][3], 0xFFFFFFC0u, tgb - (uint)(mi * 16 + 3));
        top2p(c1, c2, k0, k1);
        top2p(c1, c2, k2, k3);
      }
      #pragma unroll
      for (int off = 16; off <= 32; off <<= 1) {
        const float o1 = __shfl_xor(c1, off);
        const float o2 = __shfl_xor(c2, off);
        top2merge(c1, c2, o1, o2);
      }
      cp1 = c1; cp2 = c2;
    }
    __syncthreads();
  }

  // final partC store
  if (g == 0)
    partC[((size_t)rb * B_ + b) * N_ + cs * 2048 + (MT_ITERS - 1) * 128 + wn * 16 + l15] =
        make_uint2(__float_as_uint(cp1), __float_as_uint(cp2));

  // row merge across 16 column-lanes (l15), write per-(cs,wn) partials
  #pragma unroll
  for (int off = 1; off < 16; off <<= 1) {
    #pragma unroll
    for (int mi = 0; mi < 4; ++mi)
      #pragma unroll
      for (int rg = 0; rg < 4; ++rg) {
        const float o1 = __shfl_xor(rs1[mi][rg], off);
        const float o2 = __shfl_xor(rs2[mi][rg], off);
        top2merge(rs1[mi][rg], rs2[mi][rg], o1, o2);
      }
  }
  if (l15 == 0) {
    #pragma unroll
    for (int mi = 0; mi < 4; ++mi)
      #pragma unroll
      for (int rg = 0; rg < 4; ++rg)
        partR[((size_t)(cs * 8 + wn) * B_ + b) * N_ + r0 + mi * 16 + g * 4 + rg] =
            make_uint2(__float_as_uint(rs1[mi][rg]), __float_as_uint(rs2[mi][rg]));
  }
}

// ---- fused: fold partials, ratio test, mutual check, output ----
__global__ __launch_bounds__(256)
void finalize_kernel(const uint2* __restrict__ pR, const uint2* __restrict__ pC,
                     float* __restrict__ out)
{
  const int i = blockIdx.x * 256 + threadIdx.x;
  if (i >= B_ * N_) return;
  const int b = i >> 12;
  const int n = i & (N_ - 1);
  const float NEG = __uint_as_float(0xFF800000u);

  float s1 = NEG, s2 = NEG; int bs = 0;
  #pragma unroll
  for (int sl = 0; sl < 16; ++sl) {
    const uint2 v = pR[(size_t)sl * B_ * N_ + i];
    const float o1 = __uint_as_float(v.x), o2 = __uint_as_float(v.y);
    bs = (o1 > s1) ? sl : bs;
    top2merge(s1, s2, o1, o2);
  }
  const uint k1 = __float_as_uint(s1);
  const int col = (bs >> 3) * 2048 + 2047 - (int)(k1 & 0x7FFu);
  const float v1 = __uint_as_float(k1 & 0xFFFFF800u);
  const float v2 = __uint_as_float(__float_as_uint(s2) & 0xFFFFF800u);
  const bool ok = (1.0f - v1) <= 0.64f * (1.0f - v2);   // Lowe 0.8^2

  out[B_ * N_ + i] = ok ? (v1 + 1.0f) * 0.5f : 0.0f;    // scores0 (no mutual mask)

  int res = -1;
  if (ok) {
    float c1 = NEG, c2 = NEG; int cbs = 0;
    const uint2* pcb = pC + (size_t)b * N_ + col;
    #pragma unroll 8
    for (int sl = 0; sl < 64; ++sl) {
      const uint2 v = pcb[(size_t)sl * B_ * N_];
      const float o1 = __uint_as_float(v.x), o2 = __uint_as_float(v.y);
      cbs = (o1 > c1) ? sl : cbs;
      top2merge(c1, c2, o1, o2);
    }
    const uint ck1 = __float_as_uint(c1);
    const int row = cbs * 64 + 63 - (int)(ck1 & 0x3Fu);
    const float cv1 = __uint_as_float(ck1 & 0xFFFFFFC0u);
    const float cv2 = __uint_as_float(__float_as_uint(c2) & 0xFFFFFFC0u);
    const bool cok = (1.0f - cv1) <= 0.64f * (1.0f - cv2);
    if (cok && row == n) res = col;
  }
  out[i] = (float)res;
}

extern "C" void kernel_launch(void* const* d_in, const int* in_sizes, int n_in,
                              void* d_out, int out_size, void* d_ws, size_t ws_size,
                              hipStream_t stream)
{
  const float* d0 = (const float*)d_in[0];
  const float* d1 = (const float*)d_in[1];
  float* out = (float*)d_out;

  uchar* At = (uchar*)((char*)d_ws + OFF_AT);
  uchar* Bt = (uchar*)((char*)d_ws + OFF_BT);
  uint2* PR = (uint2*)((char*)d_ws + OFF_PR);
  uint2* PC = (uint2*)((char*)d_ws + OFF_PC);

  prep_kernel<<<dim3(N_ / 128, D_ / 32, 16), 256, 0, stream>>>(d0, d1, At, Bt);
  nn_pass<<<dim3(B_ * 64 * CSPLIT), 512, 0, stream>>>(At, Bt, PR, PC);
  finalize_kernel<<<dim3(B_ * N_ / 256), 256, 0, stream>>>(PR, PC, out);
}

// Round 12
// 137.135 us; speedup vs baseline: 1.2280x; 1.2280x over previous
//
#include <hip/hip_runtime.h>

// NearestNeighbor b=8, d=256, n=m=4096.
// Round 12: NO-LDS nn_pass — B-frags read directly from L2-resident frag-tiled
// panel (lane-linear i32x8), register-pipelined one K-half ahead, ZERO barriers.
// Contiguous-32B frag layout. prep/finalize logic verified r8-r11.

typedef unsigned int uint;
typedef unsigned char uchar;
typedef int i32x4 __attribute__((ext_vector_type(4)));
typedef int i32x8 __attribute__((ext_vector_type(8)));
typedef float f32x4 __attribute__((ext_vector_type(4)));

constexpr int B_ = 8, D_ = 256, N_ = 4096;
constexpr int CSPLIT = 2;
constexpr int MT_ITERS = (N_ / CSPLIT) / 128;   // 16 tiles of 128 cols

// Frag-tiled panel layout, contiguous 32B per lane (per batch, 1 MB):
// element (n,k): seg=n>>7, f=((n>>6)&1)*4+((n>>4)&3), i16=n&15;
//               ks=k>>7, g=(k>>5)&3, h=(k>>4)&1, kb=k&15, l=g*16+i16
// off = seg*32768 + ks*16384 + f*2048 + l*32 + h*16 + kb
// => lane l's 32B for frag (seg,ks,f) is contiguous at base + l*32.

// workspace layout (bytes)
constexpr size_t SZ_PANEL = (size_t)B_ * N_ * D_;        // 8.39 MB (fp8)
constexpr size_t OFF_AT = 0;
constexpr size_t OFF_BT = SZ_PANEL;
constexpr size_t OFF_PR = 2 * SZ_PANEL;                  // row partials: 4 slots
constexpr size_t SZ_PR  = (size_t)4 * B_ * N_ * 8;       // 1 MB
constexpr size_t OFF_PC = OFF_PR + SZ_PR;                // col partials: 64 slots

// f32 -> OCP e4m3fn (RNE, saturating).
__device__ __forceinline__ uchar f2e4m3(float f) {
  uint u = __float_as_uint(f);
  uint s = (u >> 24) & 0x80u;
  uint mag = u & 0x7FFFFFFFu;
  if (mag >= 0x43E00000u) return (uchar)(s | 0x7Eu);
  int e = (int)(mag >> 23) - 127;
  if (e >= -6) {
    uint m = (mag >> 20) & 7u;
    uint rem = mag & 0xFFFFFu;
    m += (rem > 0x80000u) || (rem == 0x80000u && (m & 1u));
    uint ef = (uint)(e + 7);
    if (m == 8u) { m = 0u; ef += 1u; }
    if (ef >= 16u) return (uchar)(s | 0x7Eu);
    return (uchar)(s | (ef << 3) | m);
  } else {
    int q = __float2int_rn(__uint_as_float(mag) * 512.0f);
    if (q >= 8) return (uchar)(s | 0x08u);
    return (uchar)(s | (uint)q);
  }
}

__device__ __forceinline__ float packkey(float v, uint mask, uint tag) {
  return __uint_as_float((__float_as_uint(v) & mask) | tag);
}

__device__ __forceinline__ float med3f(float a, float b, float c) {
#if __has_builtin(__builtin_amdgcn_fmed3f)
  return __builtin_amdgcn_fmed3f(a, b, c);
#else
  return fmaxf(fminf(a, b), fminf(fmaxf(a, b), c));
#endif
}

__device__ __forceinline__ void top2p(float& s1, float& s2, float k0, float k1) {
  const float mid = med3f(s1, k0, k1);
  s1 = fmaxf(fmaxf(s1, k0), k1);
  s2 = fmaxf(s2, mid);
}

__device__ __forceinline__ void top2merge(float& s1, float& s2, float o1, float o2) {
  const float lo = fminf(s1, o1);
  s1 = fmaxf(s1, o1);
  s2 = fmaxf(lo, fmaxf(s2, o2));
}

// ---- prep: [b][256][4096] f32 -> frag-tiled fp8 panel (contiguous-32B layout) ----
__global__ __launch_bounds__(256)
void prep_kernel(const float* __restrict__ in0, const float* __restrict__ in1,
                 uchar* __restrict__ At, uchar* __restrict__ Bt)
{
  __shared__ uchar tile[128][44];
  const int bz = blockIdx.z;
  const float* src = (bz < 8) ? in0 : in1;
  uchar* dst = (bz < 8) ? At : Bt;
  const int b = bz & 7;
  const int n0 = blockIdx.x * 128;
  const int k0b = blockIdx.y * 32;
  const int t = threadIdx.x;

  const int kq = t >> 5;
  const int n4 = (t & 31) * 4;
  const float* pin = src + ((size_t)b * D_ + k0b + kq * 4) * N_ + n0 + n4;
  float4 v[4];
  #pragma unroll
  for (int j = 0; j < 4; ++j) v[j] = *(const float4*)(pin + (size_t)j * N_);
  #pragma unroll
  for (int i = 0; i < 4; ++i) {
    uchar4 o = make_uchar4(f2e4m3(((const float*)&v[0])[i]),
                           f2e4m3(((const float*)&v[1])[i]),
                           f2e4m3(((const float*)&v[2])[i]),
                           f2e4m3(((const float*)&v[3])[i]));
    *(uchar4*)&tile[n4 + i][kq * 4] = o;
  }
  __syncthreads();

  const int nl = t & 127, h = t >> 7;
  const int kg = k0b + h * 16;
  const int ks = kg >> 7, g = (kg >> 5) & 3, hh = (kg >> 4) & 1;
  const int f = ((nl >> 6) & 1) * 4 + ((nl >> 4) & 3);
  const int l = g * 16 + (nl & 15);
  i32x4 val;
  #pragma unroll
  for (int j = 0; j < 4; ++j)
    val[j] = *(const int*)&tile[nl][h * 16 + j * 4];
  uchar* po = dst + (size_t)b * (N_ * D_) + (size_t)blockIdx.x * 32768 +
              ks * 16384 + f * 2048 + l * 32 + hh * 16;
  *(i32x4*)po = val;
}

// ---- fused GEMM (MX-fp8 K=128) + dual-direction top-2, NO LDS, NO barriers ----
// Block 256 thr = 4 waves (wm,wn), each 64x64 of a 128-row x 2048-col scan.
__global__ __launch_bounds__(256, 2)
void nn_pass(const uchar* __restrict__ A, const uchar* __restrict__ Bp,
             uint2* __restrict__ partR, uint2* __restrict__ partC)
{
  const int t = threadIdx.x;
  const int bid = blockIdx.x;
  const int b = bid & 7;                   // XCD-pinned batch (panels L2-resident)
  const int rb = (bid >> 3) & 31;
  const int cs = bid >> 8;                 // 0..1
  const size_t bOff = (size_t)b * (N_ * D_);
  const int r0 = rb * 128;

  const int l = t & 63, wid = t >> 6, wm = wid >> 1, wn = wid & 1;
  const int l15 = l & 15, g = l >> 4;

  const uchar* Aseg = A + bOff + (size_t)rb * 32768;
  const uchar* Bb = Bp + bOff + (size_t)cs * 524288;   // cs half: 16 tiles x 32KB

  // ---- A-frags resident in registers (64 VGPR), single i32x8 loads ----
  i32x8 af0[4], af1[4];
  #pragma unroll
  for (int mi = 0; mi < 4; ++mi) {
    af0[mi] = *(const i32x8*)(Aseg +         (wm * 4 + mi) * 2048 + l * 32);
    af1[mi] = *(const i32x8*)(Aseg + 16384 + (wm * 4 + mi) * 2048 + l * 32);
  }

  const float NEG = __uint_as_float(0xFF800000u);  // -inf
  float rs1[4][4], rs2[4][4];
  #pragma unroll
  for (int mi = 0; mi < 4; ++mi)
    #pragma unroll
    for (int rg = 0; rg < 4; ++rg) { rs1[mi][rg] = NEG; rs2[mi][rg] = NEG; }

  // B-frag loader: 4 ni frags of K-half ks for tile mt (L2/L1-hot, lane-linear)
  auto LOADB = [&](i32x8 (&dst)[4], int mt, int ks) {
    const uchar* p = Bb + (size_t)mt * 32768 + ks * 16384 + wn * 8192 + l * 32;
    #pragma unroll
    for (int ni = 0; ni < 4; ++ni)
      dst[ni] = *(const i32x8*)(p + ni * 2048);
  };

  auto MFMAH = [&](const i32x8 (&afk)[4], const i32x8 (&bf)[4], f32x4 (&acc)[4][4]) {
    __builtin_amdgcn_s_setprio(1);
    #pragma unroll
    for (int ni = 0; ni < 4; ++ni)
      #pragma unroll
      for (int mi = 0; mi < 4; ++mi)
        acc[mi][ni] = __builtin_amdgcn_mfma_scale_f32_16x16x128_f8f6f4(
            afk[mi], bf[ni], acc[mi][ni], 0, 0, 0, 127, 0, 127);
    __builtin_amdgcn_s_setprio(0);
  };

  auto FOLD = [&](int mt, f32x4 (&acc)[4][4]) {
    const int colb = mt * 128 + wn * 64;
    const uint tg0 = (uint)(2047 - (colb + l15));
    #pragma unroll
    for (int mi = 0; mi < 4; ++mi)
      #pragma unroll
      for (int rg = 0; rg < 4; ++rg) {
        const float k0 = packkey(acc[mi][0][rg], 0xFFFFF800u, tg0);
        const float k1 = packkey(acc[mi][1][rg], 0xFFFFF800u, tg0 - 16);
        const float k2 = packkey(acc[mi][2][rg], 0xFFFFF800u, tg0 - 32);
        const float k3 = packkey(acc[mi][3][rg], 0xFFFFF800u, tg0 - 48);
        top2p(rs1[mi][rg], rs2[mi][rg], k0, k1);
        top2p(rs1[mi][rg], rs2[mi][rg], k2, k3);
      }
    const uint tgb = (uint)(63 - g * 4);
    #pragma unroll
    for (int ni = 0; ni < 4; ++ni) {
      float c1 = NEG, c2 = NEG;
      #pragma unroll
      for (int mi = 0; mi < 4; ++mi) {
        const float k0 = packkey(acc[mi][ni][0], 0xFFFFFFC0u, tgb - (uint)(mi * 16));
        const float k1 = packkey(acc[mi][ni][1], 0xFFFFFFC0u, tgb - (uint)(mi * 16 + 1));
        const float k2 = packkey(acc[mi][ni][2], 0xFFFFFFC0u, tgb - (uint)(mi * 16 + 2));
        const float k3 = packkey(acc[mi][ni][3], 0xFFFFFFC0u, tgb - (uint)(mi * 16 + 3));
        top2p(c1, c2, k0, k1);
        top2p(c1, c2, k2, k3);
      }
      #pragma unroll
      for (int off = 16; off <= 32; off <<= 1) {
        const float o1 = __shfl_xor(c1, off);
        const float o2 = __shfl_xor(c2, off);
        top2merge(c1, c2, o1, o2);
      }
      if (g == 0)   // wave-private slot: no sync needed
        partC[((size_t)(rb * 2 + wm) * B_ + b) * N_ + cs * 2048 + colb + ni * 16 + l15] =
            make_uint2(__float_as_uint(c1), __float_as_uint(c2));
    }
  };

  // one tile: compute (pf = prefetched ks0) and prefetch next tile's ks0 into nx
  auto TILE = [&](int mt, i32x8 (&pf)[4], i32x8 (&nx)[4]) {
    f32x4 acc[4][4];
    #pragma unroll
    for (int mi = 0; mi < 4; ++mi)
      #pragma unroll
      for (int ni = 0; ni < 4; ++ni) acc[mi][ni] = (f32x4){0.f, 0.f, 0.f, 0.f};
    i32x8 b1[4];
    LOADB(b1, mt, 1);                 // ks1 loads hide under ks0 MFMAs
    MFMAH(af0, pf, acc);
    LOADB(nx, (mt + 1) & 15, 0);      // next-tile ks0 (wraps harmlessly at end)
    MFMAH(af1, b1, acc);
    FOLD(mt, acc);
  };

  i32x8 pfA[4], pfB[4];
  LOADB(pfA, 0, 0);

  #pragma unroll 1
  for (int mt = 0; mt < MT_ITERS; mt += 2) {
    TILE(mt,     pfA, pfB);           // static alternation: no runtime indexing
    TILE(mt + 1, pfB, pfA);
  }

  // epilogue: row merge across 16 column-lanes, write per-(cs,wn) partials
  #pragma unroll
  for (int off = 1; off < 16; off <<= 1) {
    #pragma unroll
    for (int mi = 0; mi < 4; ++mi)
      #pragma unroll
      for (int rg = 0; rg < 4; ++rg) {
        const float o1 = __shfl_xor(rs1[mi][rg], off);
        const float o2 = __shfl_xor(rs2[mi][rg], off);
        top2merge(rs1[mi][rg], rs2[mi][rg], o1, o2);
      }
  }
  if (l15 == 0) {
    #pragma unroll
    for (int mi = 0; mi < 4; ++mi)
      #pragma unroll
      for (int rg = 0; rg < 4; ++rg)
        partR[((size_t)(cs * 2 + wn) * B_ + b) * N_ + r0 + wm * 64 + mi * 16 + g * 4 + rg] =
            make_uint2(__float_as_uint(rs1[mi][rg]), __float_as_uint(rs2[mi][rg]));
  }
}

// ---- fused: fold partials, ratio test, mutual check, output (verified r9/r10) ----
__global__ __launch_bounds__(256)
void finalize_kernel(const uint2* __restrict__ pR, const uint2* __restrict__ pC,
                     float* __restrict__ out)
{
  const int i = blockIdx.x * 256 + threadIdx.x;
  if (i >= B_ * N_) return;
  const int b = i >> 12;
  const int n = i & (N_ - 1);
  const float NEG = __uint_as_float(0xFF800000u);

  float s1 = NEG, s2 = NEG; int bs = 0;
  #pragma unroll
  for (int sl = 0; sl < 4; ++sl) {
    const uint2 v = pR[(size_t)sl * B_ * N_ + i];
    const float o1 = __uint_as_float(v.x), o2 = __uint_as_float(v.y);
    bs = (o1 > s1) ? sl : bs;
    top2merge(s1, s2, o1, o2);
  }
  const uint k1 = __float_as_uint(s1);
  const int col = (bs >> 1) * 2048 + 2047 - (int)(k1 & 0x7FFu);
  const float v1 = __uint_as_float(k1 & 0xFFFFF800u);
  const float v2 = __uint_as_float(__float_as_uint(s2) & 0xFFFFF800u);
  const bool ok = (1.0f - v1) <= 0.64f * (1.0f - v2);   // Lowe 0.8^2

  out[B_ * N_ + i] = ok ? (v1 + 1.0f) * 0.5f : 0.0f;    // scores0 (no mutual mask)

  int res = -1;
  if (ok) {
    float c1 = NEG, c2 = NEG; int cbs = 0;
    const uint2* pcb = pC + (size_t)b * N_ + col;
    #pragma unroll 8
    for (int sl = 0; sl < 64; ++sl) {
      const uint2 v = pcb[(size_t)sl * B_ * N_];
      const float o1 = __uint_as_float(v.x), o2 = __uint_as_float(v.y);
      cbs = (o1 > c1) ? sl : cbs;
      top2merge(c1, c2, o1, o2);
    }
    const uint ck1 = __float_as_uint(c1);
    const int row = cbs * 64 + 63 - (int)(ck1 & 0x3Fu);
    const float cv1 = __uint_as_float(ck1 & 0xFFFFFFC0u);
    const float cv2 = __uint_as_float(__float_as_uint(c2) & 0xFFFFFFC0u);
    const bool cok = (1.0f - cv1) <= 0.64f * (1.0f - cv2);
    if (cok && row == n) res = col;
  }
  out[i] = (float)res;
}

extern "C" void kernel_launch(void* const* d_in, const int* in_sizes, int n_in,
                              void* d_out, int out_size, void* d_ws, size_t ws_size,
                              hipStream_t stream)
{
  const float* d0 = (const float*)d_in[0];
  const float* d1 = (const float*)d_in[1];
  float* out = (float*)d_out;

  uchar* At = (uchar*)((char*)d_ws + OFF_AT);
  uchar* Bt = (uchar*)((char*)d_ws + OFF_BT);
  uint2* PR = (uint2*)((char*)d_ws + OFF_PR);
  uint2* PC = (uint2*)((char*)d_ws + OFF_PC);

  prep_kernel<<<dim3(N_ / 128, D_ / 32, 16), 256, 0, stream>>>(d0, d1, At, Bt);
  nn_pass<<<dim3(B_ * 32 * CSPLIT), 256, 0, stream>>>(At, Bt, PR, PC);
  finalize_kernel<<<dim3(B_ * N_ / 256), 256, 0, stream>>>(PR, PC, out);
}

// Round 13
// 74.910 us; speedup vs baseline: 2.2481x; 1.8307x over previous
//
#include <hip/hip_runtime.h>

// NearestNeighbor b=8, d=256, n=m=4096.
// Round 13: NO-LDS nn_pass, register-honest: per tile load 8 B-frags (64 VGPR
// transient) from the L2-resident frag-tiled panel, 32 MFMAs, fold. Zero
// barriers, zero LDS. Layout/folds/prep/finalize byte-identical to r12 (verified).

typedef unsigned int uint;
typedef unsigned char uchar;
typedef int i32x4 __attribute__((ext_vector_type(4)));
typedef int i32x8 __attribute__((ext_vector_type(8)));
typedef float f32x4 __attribute__((ext_vector_type(4)));

constexpr int B_ = 8, D_ = 256, N_ = 4096;
constexpr int CSPLIT = 2;
constexpr int MT_ITERS = (N_ / CSPLIT) / 128;   // 16 tiles of 128 cols

// Frag-tiled panel layout, contiguous 32B per lane (per batch, 1 MB):
// element (n,k): seg=n>>7, f=((n>>6)&1)*4+((n>>4)&3), i16=n&15;
//               ks=k>>7, g=(k>>5)&3, h=(k>>4)&1, kb=k&15, l=g*16+i16
// off = seg*32768 + ks*16384 + f*2048 + l*32 + h*16 + kb

// workspace layout (bytes)
constexpr size_t SZ_PANEL = (size_t)B_ * N_ * D_;        // 8.39 MB (fp8)
constexpr size_t OFF_AT = 0;
constexpr size_t OFF_BT = SZ_PANEL;
constexpr size_t OFF_PR = 2 * SZ_PANEL;                  // row partials: 4 slots
constexpr size_t SZ_PR  = (size_t)4 * B_ * N_ * 8;       // 1 MB
constexpr size_t OFF_PC = OFF_PR + SZ_PR;                // col partials: 64 slots

// f32 -> OCP e4m3fn (RNE, saturating).
__device__ __forceinline__ uchar f2e4m3(float f) {
  uint u = __float_as_uint(f);
  uint s = (u >> 24) & 0x80u;
  uint mag = u & 0x7FFFFFFFu;
  if (mag >= 0x43E00000u) return (uchar)(s | 0x7Eu);
  int e = (int)(mag >> 23) - 127;
  if (e >= -6) {
    uint m = (mag >> 20) & 7u;
    uint rem = mag & 0xFFFFFu;
    m += (rem > 0x80000u) || (rem == 0x80000u && (m & 1u));
    uint ef = (uint)(e + 7);
    if (m == 8u) { m = 0u; ef += 1u; }
    if (ef >= 16u) return (uchar)(s | 0x7Eu);
    return (uchar)(s | (ef << 3) | m);
  } else {
    int q = __float2int_rn(__uint_as_float(mag) * 512.0f);
    if (q >= 8) return (uchar)(s | 0x08u);
    return (uchar)(s | (uint)q);
  }
}

__device__ __forceinline__ float packkey(float v, uint mask, uint tag) {
  return __uint_as_float((__float_as_uint(v) & mask) | tag);
}

__device__ __forceinline__ float med3f(float a, float b, float c) {
#if __has_builtin(__builtin_amdgcn_fmed3f)
  return __builtin_amdgcn_fmed3f(a, b, c);
#else
  return fmaxf(fminf(a, b), fminf(fmaxf(a, b), c));
#endif
}

__device__ __forceinline__ void top2p(float& s1, float& s2, float k0, float k1) {
  const float mid = med3f(s1, k0, k1);
  s1 = fmaxf(fmaxf(s1, k0), k1);
  s2 = fmaxf(s2, mid);
}

__device__ __forceinline__ void top2merge(float& s1, float& s2, float o1, float o2) {
  const float lo = fminf(s1, o1);
  s1 = fmaxf(s1, o1);
  s2 = fmaxf(lo, fmaxf(s2, o2));
}

// ---- prep: [b][256][4096] f32 -> frag-tiled fp8 panel (verified r12) ----
__global__ __launch_bounds__(256)
void prep_kernel(const float* __restrict__ in0, const float* __restrict__ in1,
                 uchar* __restrict__ At, uchar* __restrict__ Bt)
{
  __shared__ uchar tile[128][44];
  const int bz = blockIdx.z;
  const float* src = (bz < 8) ? in0 : in1;
  uchar* dst = (bz < 8) ? At : Bt;
  const int b = bz & 7;
  const int n0 = blockIdx.x * 128;
  const int k0b = blockIdx.y * 32;
  const int t = threadIdx.x;

  const int kq = t >> 5;
  const int n4 = (t & 31) * 4;
  const float* pin = src + ((size_t)b * D_ + k0b + kq * 4) * N_ + n0 + n4;
  float4 v[4];
  #pragma unroll
  for (int j = 0; j < 4; ++j) v[j] = *(const float4*)(pin + (size_t)j * N_);
  #pragma unroll
  for (int i = 0; i < 4; ++i) {
    uchar4 o = make_uchar4(f2e4m3(((const float*)&v[0])[i]),
                           f2e4m3(((const float*)&v[1])[i]),
                           f2e4m3(((const float*)&v[2])[i]),
                           f2e4m3(((const float*)&v[3])[i]));
    *(uchar4*)&tile[n4 + i][kq * 4] = o;
  }
  __syncthreads();

  const int nl = t & 127, h = t >> 7;
  const int kg = k0b + h * 16;
  const int ks = kg >> 7, g = (kg >> 5) & 3, hh = (kg >> 4) & 1;
  const int f = ((nl >> 6) & 1) * 4 + ((nl >> 4) & 3);
  const int l = g * 16 + (nl & 15);
  i32x4 val;
  #pragma unroll
  for (int j = 0; j < 4; ++j)
    val[j] = *(const int*)&tile[nl][h * 16 + j * 4];
  uchar* po = dst + (size_t)b * (N_ * D_) + (size_t)blockIdx.x * 32768 +
              ks * 16384 + f * 2048 + l * 32 + hh * 16;
  *(i32x4*)po = val;
}

// ---- fused GEMM (MX-fp8 K=128) + dual-direction top-2, NO LDS, NO barriers ----
// Block 256 thr = 4 waves (wm,wn), each 64x64 of a 128-row x 2048-col scan.
__global__ __launch_bounds__(256, 2)
void nn_pass(const uchar* __restrict__ A, const uchar* __restrict__ Bp,
             uint2* __restrict__ partR, uint2* __restrict__ partC)
{
  const int t = threadIdx.x;
  const int bid = blockIdx.x;
  const int b = bid & 7;                   // XCD-pinned batch (panels L2-resident)
  const int rb = (bid >> 3) & 31;
  const int cs = bid >> 8;                 // 0..1
  const size_t bOff = (size_t)b * (N_ * D_);
  const int r0 = rb * 128;

  const int l = t & 63, wid = t >> 6, wm = wid >> 1, wn = wid & 1;
  const int l15 = l & 15, g = l >> 4;

  const uchar* Aseg = A + bOff + (size_t)rb * 32768;
  const uchar* Bb = Bp + bOff + (size_t)cs * 524288;   // cs half: 16 tiles x 32KB

  // ---- A-frags resident in registers (64 VGPR) ----
  i32x8 af0[4], af1[4];
  #pragma unroll
  for (int mi = 0; mi < 4; ++mi) {
    af0[mi] = *(const i32x8*)(Aseg +         (wm * 4 + mi) * 2048 + l * 32);
    af1[mi] = *(const i32x8*)(Aseg + 16384 + (wm * 4 + mi) * 2048 + l * 32);
  }

  const float NEG = __uint_as_float(0xFF800000u);  // -inf
  float rs1[4][4], rs2[4][4];
  #pragma unroll
  for (int mi = 0; mi < 4; ++mi)
    #pragma unroll
    for (int rg = 0; rg < 4; ++rg) { rs1[mi][rg] = NEG; rs2[mi][rg] = NEG; }

  #pragma unroll 1
  for (int mt = 0; mt < MT_ITERS; ++mt) {
    const uchar* pB = Bb + (size_t)mt * 32768 + wn * 8192 + l * 32;

    // 8 B-frags for this tile (both K-halves): 64 transient VGPR, L2-hot
    const i32x8 b00 = *(const i32x8*)(pB);
    const i32x8 b01 = *(const i32x8*)(pB + 2048);
    const i32x8 b02 = *(const i32x8*)(pB + 4096);
    const i32x8 b03 = *(const i32x8*)(pB + 6144);
    const i32x8 b10 = *(const i32x8*)(pB + 16384);
    const i32x8 b11 = *(const i32x8*)(pB + 16384 + 2048);
    const i32x8 b12 = *(const i32x8*)(pB + 16384 + 4096);
    const i32x8 b13 = *(const i32x8*)(pB + 16384 + 6144);

    f32x4 acc[4][4];
    #pragma unroll
    for (int mi = 0; mi < 4; ++mi)
      #pragma unroll
      for (int ni = 0; ni < 4; ++ni) acc[mi][ni] = (f32x4){0.f, 0.f, 0.f, 0.f};

    __builtin_amdgcn_s_setprio(1);
    #pragma unroll
    for (int mi = 0; mi < 4; ++mi) {
      acc[mi][0] = __builtin_amdgcn_mfma_scale_f32_16x16x128_f8f6f4(af0[mi], b00, acc[mi][0], 0, 0, 0, 127, 0, 127);
      acc[mi][1] = __builtin_amdgcn_mfma_scale_f32_16x16x128_f8f6f4(af0[mi], b01, acc[mi][1], 0, 0, 0, 127, 0, 127);
      acc[mi][2] = __builtin_amdgcn_mfma_scale_f32_16x16x128_f8f6f4(af0[mi], b02, acc[mi][2], 0, 0, 0, 127, 0, 127);
      acc[mi][3] = __builtin_amdgcn_mfma_scale_f32_16x16x128_f8f6f4(af0[mi], b03, acc[mi][3], 0, 0, 0, 127, 0, 127);
    }
    #pragma unroll
    for (int mi = 0; mi < 4; ++mi) {
      acc[mi][0] = __builtin_amdgcn_mfma_scale_f32_16x16x128_f8f6f4(af1[mi], b10, acc[mi][0], 0, 0, 0, 127, 0, 127);
      acc[mi][1] = __builtin_amdgcn_mfma_scale_f32_16x16x128_f8f6f4(af1[mi], b11, acc[mi][1], 0, 0, 0, 127, 0, 127);
      acc[mi][2] = __builtin_amdgcn_mfma_scale_f32_16x16x128_f8f6f4(af1[mi], b12, acc[mi][2], 0, 0, 0, 127, 0, 127);
      acc[mi][3] = __builtin_amdgcn_mfma_scale_f32_16x16x128_f8f6f4(af1[mi], b13, acc[mi][3], 0, 0, 0, 127, 0, 127);
    }
    __builtin_amdgcn_s_setprio(0);

    // ---- fold: row direction (persistent rs) ----
    const int colb = mt * 128 + wn * 64;
    const uint tg0 = (uint)(2047 - (colb + l15));
    #pragma unroll
    for (int mi = 0; mi < 4; ++mi)
      #pragma unroll
      for (int rg = 0; rg < 4; ++rg) {
        const float k0 = packkey(acc[mi][0][rg], 0xFFFFF800u, tg0);
        const float k1 = packkey(acc[mi][1][rg], 0xFFFFF800u, tg0 - 16);
        const float k2 = packkey(acc[mi][2][rg], 0xFFFFF800u, tg0 - 32);
        const float k3 = packkey(acc[mi][3][rg], 0xFFFFF800u, tg0 - 48);
        top2p(rs1[mi][rg], rs2[mi][rg], k0, k1);
        top2p(rs1[mi][rg], rs2[mi][rg], k2, k3);
      }

    // ---- fold: col direction (per tile; wave-private partC slot) ----
    const uint tgb = (uint)(63 - g * 4);
    #pragma unroll
    for (int ni = 0; ni < 4; ++ni) {
      float c1 = NEG, c2 = NEG;
      #pragma unroll
      for (int mi = 0; mi < 4; ++mi) {
        const float k0 = packkey(acc[mi][ni][0], 0xFFFFFFC0u, tgb - (uint)(mi * 16));
        const float k1 = packkey(acc[mi][ni][1], 0xFFFFFFC0u, tgb - (uint)(mi * 16 + 1));
        const float k2 = packkey(acc[mi][ni][2], 0xFFFFFFC0u, tgb - (uint)(mi * 16 + 2));
        const float k3 = packkey(acc[mi][ni][3], 0xFFFFFFC0u, tgb - (uint)(mi * 16 + 3));
        top2p(c1, c2, k0, k1);
        top2p(c1, c2, k2, k3);
      }
      #pragma unroll
      for (int off = 16; off <= 32; off <<= 1) {
        const float o1 = __shfl_xor(c1, off);
        const float o2 = __shfl_xor(c2, off);
        top2merge(c1, c2, o1, o2);
      }
      if (g == 0)
        partC[((size_t)(rb * 2 + wm) * B_ + b) * N_ + cs * 2048 + colb + ni * 16 + l15] =
            make_uint2(__float_as_uint(c1), __float_as_uint(c2));
    }
  }

  // epilogue: row merge across 16 column-lanes, write per-(cs,wn) partials
  #pragma unroll
  for (int off = 1; off < 16; off <<= 1) {
    #pragma unroll
    for (int mi = 0; mi < 4; ++mi)
      #pragma unroll
      for (int rg = 0; rg < 4; ++rg) {
        const float o1 = __shfl_xor(rs1[mi][rg], off);
        const float o2 = __shfl_xor(rs2[mi][rg], off);
        top2merge(rs1[mi][rg], rs2[mi][rg], o1, o2);
      }
  }
  if (l15 == 0) {
    #pragma unroll
    for (int mi = 0; mi < 4; ++mi)
      #pragma unroll
      for (int rg = 0; rg < 4; ++rg)
        partR[((size_t)(cs * 2 + wn) * B_ + b) * N_ + r0 + wm * 64 + mi * 16 + g * 4 + rg] =
            make_uint2(__float_as_uint(rs1[mi][rg]), __float_as_uint(rs2[mi][rg]));
  }
}

// ---- fused: fold partials, ratio test, mutual check, output (verified r9-r12) ----
__global__ __launch_bounds__(256)
void finalize_kernel(const uint2* __restrict__ pR, const uint2* __restrict__ pC,
                     float* __restrict__ out)
{
  const int i = blockIdx.x * 256 + threadIdx.x;
  if (i >= B_ * N_) return;
  const int b = i >> 12;
  const int n = i & (N_ - 1);
  const float NEG = __uint_as_float(0xFF800000u);

  float s1 = NEG, s2 = NEG; int bs = 0;
  #pragma unroll
  for (int sl = 0; sl < 4; ++sl) {
    const uint2 v = pR[(size_t)sl * B_ * N_ + i];
    const float o1 = __uint_as_float(v.x), o2 = __uint_as_float(v.y);
    bs = (o1 > s1) ? sl : bs;
    top2merge(s1, s2, o1, o2);
  }
  const uint k1 = __float_as_uint(s1);
  const int col = (bs >> 1) * 2048 + 2047 - (int)(k1 & 0x7FFu);
  const float v1 = __uint_as_float(k1 & 0xFFFFF800u);
  const float v2 = __uint_as_float(__float_as_uint(s2) & 0xFFFFF800u);
  const bool ok = (1.0f - v1) <= 0.64f * (1.0f - v2);   // Lowe 0.8^2

  out[B_ * N_ + i] = ok ? (v1 + 1.0f) * 0.5f : 0.0f;    // scores0 (no mutual mask)

  int res = -1;
  if (ok) {
    float c1 = NEG, c2 = NEG; int cbs = 0;
    const uint2* pcb = pC + (size_t)b * N_ + col;
    #pragma unroll 8
    for (int sl = 0; sl < 64; ++sl) {
      const uint2 v = pcb[(size_t)sl * B_ * N_];
      const float o1 = __uint_as_float(v.x), o2 = __uint_as_float(v.y);
      cbs = (o1 > c1) ? sl : cbs;
      top2merge(c1, c2, o1, o2);
    }
    const uint ck1 = __float_as_uint(c1);
    const int row = cbs * 64 + 63 - (int)(ck1 & 0x3Fu);
    const float cv1 = __uint_as_float(ck1 & 0xFFFFFFC0u);
    const float cv2 = __uint_as_float(__float_as_uint(c2) & 0xFFFFFFC0u);
    const bool cok = (1.0f - cv1) <= 0.64f * (1.0f - cv2);
    if (cok && row == n) res = col;
  }
  out[i] = (float)res;
}

extern "C" void kernel_launch(void* const* d_in, const int* in_sizes, int n_in,
                              void* d_out, int out_size, void* d_ws, size_t ws_size,
                              hipStream_t stream)
{
  const float* d0 = (const float*)d_in[0];
  const float* d1 = (const float*)d_in[1];
  float* out = (float*)d_out;

  uchar* At = (uchar*)((char*)d_ws + OFF_AT);
  uchar* Bt = (uchar*)((char*)d_ws + OFF_BT);
  uint2* PR = (uint2*)((char*)d_ws + OFF_PR);
  uint2* PC = (uint2*)((char*)d_ws + OFF_PC);

  prep_kernel<<<dim3(N_ / 128, D_ / 32, 16), 256, 0, stream>>>(d0, d1, At, Bt);
  nn_pass<<<dim3(B_ * 32 * CSPLIT), 256, 0, stream>>>(At, Bt, PR, PC);
  finalize_kernel<<<dim3(B_ * N_ / 256), 256, 0, stream>>>(PR, PC, out);
}